// Round 2
// baseline (4115.075 us; speedup 1.0000x reference)
//
#include <hip/hip_runtime.h>
#include <hip/hip_bf16.h>

#define NN 100000
#define EE 1600000
#define GG 1000
#define DIMH 256
#define NDEPTH 4
static constexpr float EPSV = 1e-5f;

typedef unsigned short ushort;
typedef __attribute__((ext_vector_type(8))) ushort ushort8v;

__device__ __forceinline__ float bf2f(ushort u) {
    return __uint_as_float(((unsigned)u) << 16);
}
__device__ __forceinline__ ushort f2bf(float f) {
    unsigned u = __float_as_uint(f);
    unsigned r = u + 0x7FFFu + ((u >> 16) & 1u);   // RNE
    return (ushort)(r >> 16);
}

// ---------------- CSR build ----------------
__global__ __launch_bounds__(256) void k_graph_bounds(const int* __restrict__ batch, int* __restrict__ gstart) {
    int g = blockIdx.x * 256 + threadIdx.x;
    if (g > GG) return;
    int lo = 0, hi = NN;
    while (lo < hi) { int mid = (lo + hi) >> 1; if (batch[mid] < g) lo = mid + 1; else hi = mid; }
    gstart[g] = lo;
}

__global__ __launch_bounds__(256) void k_hist(const int* __restrict__ dst, int* __restrict__ deg) {
    int e = blockIdx.x * 256 + threadIdx.x;
    if (e < EE) atomicAdd(&deg[dst[e]], 1);
}

__global__ __launch_bounds__(256) void k_scan_a(const int* __restrict__ deg, int* __restrict__ rs, int* __restrict__ part) {
    __shared__ int s[256];
    int t = threadIdx.x;
    int i = blockIdx.x * 256 + t;
    int v = (i < NN) ? deg[i] : 0;
    s[t] = v; __syncthreads();
    for (int off = 1; off < 256; off <<= 1) {
        int u = (t >= off) ? s[t - off] : 0;
        __syncthreads();
        s[t] += u;
        __syncthreads();
    }
    if (i < NN) rs[i] = s[t] - v;
    if (t == 255) part[blockIdx.x] = s[255];
}

__global__ __launch_bounds__(512) void k_scan_b(int* __restrict__ part, int nb, int* __restrict__ rs) {
    __shared__ int s[512];
    int t = threadIdx.x;
    int v = (t < nb) ? part[t] : 0;
    s[t] = v; __syncthreads();
    for (int off = 1; off < 512; off <<= 1) {
        int u = (t >= off) ? s[t - off] : 0;
        __syncthreads();
        s[t] += u;
        __syncthreads();
    }
    if (t < nb) part[t] = s[t] - v;  // exclusive
    if (t == 0) rs[NN] = EE;
}

__global__ __launch_bounds__(256) void k_scan_c(int* __restrict__ rs, const int* __restrict__ part) {
    int i = blockIdx.x * 256 + threadIdx.x;
    if (i < NN) rs[i] += part[blockIdx.x];
}

__global__ __launch_bounds__(256) void k_copy_int(const int* __restrict__ a, int* __restrict__ b, int n) {
    int i = blockIdx.x * 256 + threadIdx.x;
    if (i < n) b[i] = a[i];
}

__global__ __launch_bounds__(256) void k_scatter(const int* __restrict__ src, const int* __restrict__ dst,
                                                 int* __restrict__ cursor, int* __restrict__ col) {
    int e = blockIdx.x * 256 + threadIdx.x;
    if (e >= EE) return;
    int d = dst[e];
    int pos = atomicAdd(&cursor[d], 1);
    col[pos] = src[e];
}

// ---------------- node encoder: x = emb_node[idx] + emb_depth[dep]  (bf16 out) ----------------
__global__ __launch_bounds__(256) void k_encoder(const int* __restrict__ xidx, const int* __restrict__ ndep,
                                                 const float* __restrict__ en, const float* __restrict__ ed,
                                                 ushort* __restrict__ x) {
    int gi = blockIdx.x * 256 + threadIdx.x;     // = node*64 + q  (4 features per thread)
    int node = gi >> 6, q = gi & 63;
    if (node >= NN) return;
    float4 va = ((const float4*)en)[(size_t)xidx[node] * 64 + q];
    float4 vb = ((const float4*)ed)[(size_t)ndep[node] * 64 + q];
    ushort4 o;
    o.x = f2bf(va.x + vb.x); o.y = f2bf(va.y + vb.y);
    o.z = f2bf(va.z + vb.z); o.w = f2bf(va.w + vb.w);
    ((ushort4*)x)[gi] = o;
}

// ---------------- GIN aggregate: h = x + sum_{j->i} x_j  (bf16 in/out, f32 accum) ----------------
__global__ __launch_bounds__(256) void k_aggregate(const ushort* __restrict__ x, const int* __restrict__ rs,
                                                   const int* __restrict__ col, ushort* __restrict__ hb) {
    int node = blockIdx.x * 4 + (threadIdx.x >> 6);
    int lane = threadIdx.x & 63;
    if (node >= NN) return;
    const ushort4* x4 = (const ushort4*)x;
    ushort4 sv = x4[(size_t)node * 64 + lane];
    float a0 = bf2f(sv.x), a1 = bf2f(sv.y), a2 = bf2f(sv.z), a3 = bf2f(sv.w);
    int s = rs[node], e = rs[node + 1];
    for (int j = s; j < e; j++) {
        int c = col[j];
        ushort4 v = x4[(size_t)c * 64 + lane];
        a0 += bf2f(v.x); a1 += bf2f(v.y); a2 += bf2f(v.z); a3 += bf2f(v.w);
    }
    ushort4 o; o.x = f2bf(a0); o.y = f2bf(a1); o.z = f2bf(a2); o.w = f2bf(a3);
    ((ushort4*)hb)[(size_t)node * 64 + lane] = o;
}

// ---------------- tiled GEMM: C[M,256] = act(A_bf16[M,256] @ B_f32[256,256] + bias), C bf16 ----------------
template<bool RELU>
__global__ __launch_bounds__(256) void k_gemm(const ushort* __restrict__ A, const float* __restrict__ B,
                                              const float* __restrict__ bias, ushort* __restrict__ C, int M) {
    __shared__ float As[16][128];
    __shared__ float Bs[16][128];
    int tid = threadIdx.x;
    int tx = tid & 15, ty = tid >> 4;
    int row0 = blockIdx.x * 128, col0 = blockIdx.y * 128;
    float acc[8][8];
#pragma unroll
    for (int i = 0; i < 8; i++)
#pragma unroll
        for (int j = 0; j < 8; j++) acc[i][j] = 0.f;
    int ar = tid >> 1, ah = (tid & 1) * 8;   // 2 threads per tile row, 8 bf16 (16B) each
    int br = tid >> 4, bc = (tid & 15) * 8;
    for (int k0 = 0; k0 < 256; k0 += 16) {
        int grow = row0 + ar;
        ushort8v av = (ushort8v)0;
        if (grow < M) av = *(const ushort8v*)(A + (size_t)grow * 256 + k0 + ah);
#pragma unroll
        for (int i = 0; i < 8; i++) As[ah + i][ar] = bf2f(av[i]);
        const float* bp = B + (size_t)(k0 + br) * 256 + col0 + bc;
        *(float4*)&Bs[br][bc]     = *(const float4*)bp;
        *(float4*)&Bs[br][bc + 4] = *(const float4*)(bp + 4);
        __syncthreads();
#pragma unroll
        for (int kk = 0; kk < 16; kk++) {
            float a[8], b[8];
#pragma unroll
            for (int j = 0; j < 8; j++) { a[j] = As[kk][ty * 8 + j]; b[j] = Bs[kk][tx * 8 + j]; }
#pragma unroll
            for (int i = 0; i < 8; i++)
#pragma unroll
                for (int j = 0; j < 8; j++) acc[i][j] = fmaf(a[i], b[j], acc[i][j]);
        }
        __syncthreads();
    }
#pragma unroll
    for (int i = 0; i < 8; i++) {
        int row = row0 + ty * 8 + i;
        if (row < M) {
#pragma unroll
            for (int j = 0; j < 8; j++) {
                int colc = col0 + tx * 8 + j;
                float v = acc[i][j] + bias[colc];
                if (RELU) v = fmaxf(v, 0.f);
                C[(size_t)row * 256 + colc] = f2bf(v);
            }
        }
    }
}

// ---------------- fused attention gate: gate = relu(X@W1 + b1) @ w2 + b2 ----------------
// X bf16 [M,256], W1 f32 [256,512], w2 f32 [512]. One block = 128 rows; 4 col-chunks of 128.
__global__ __launch_bounds__(256) void k_attgate(const ushort* __restrict__ X, const float* __restrict__ W1,
                                                 const float* __restrict__ b1, const float* __restrict__ w2,
                                                 const float* __restrict__ b2, float* __restrict__ gate, int M) {
    __shared__ float As[16][128];
    __shared__ float Bs[16][128];
    __shared__ float gred[128][17];
    int tid = threadIdx.x;
    int tx = tid & 15, ty = tid >> 4;
    int row0 = blockIdx.x * 128;
    int ar = tid >> 1, ah = (tid & 1) * 8;
    int br = tid >> 4, bc = (tid & 15) * 8;
    float ga[8];
#pragma unroll
    for (int i = 0; i < 8; i++) ga[i] = 0.f;

    for (int cc = 0; cc < 4; cc++) {
        int col0 = cc * 128;
        float acc[8][8];
#pragma unroll
        for (int i = 0; i < 8; i++)
#pragma unroll
            for (int j = 0; j < 8; j++) acc[i][j] = 0.f;
        for (int k0 = 0; k0 < 256; k0 += 16) {
            int grow = row0 + ar;
            ushort8v av = (ushort8v)0;
            if (grow < M) av = *(const ushort8v*)(X + (size_t)grow * 256 + k0 + ah);
#pragma unroll
            for (int i = 0; i < 8; i++) As[ah + i][ar] = bf2f(av[i]);
            const float* bp = W1 + (size_t)(k0 + br) * 512 + col0 + bc;
            *(float4*)&Bs[br][bc]     = *(const float4*)bp;
            *(float4*)&Bs[br][bc + 4] = *(const float4*)(bp + 4);
            __syncthreads();
#pragma unroll
            for (int kk = 0; kk < 16; kk++) {
                float a[8], b[8];
#pragma unroll
                for (int j = 0; j < 8; j++) { a[j] = As[kk][ty * 8 + j]; b[j] = Bs[kk][tx * 8 + j]; }
#pragma unroll
                for (int i = 0; i < 8; i++)
#pragma unroll
                    for (int j = 0; j < 8; j++) acc[i][j] = fmaf(a[i], b[j], acc[i][j]);
            }
            __syncthreads();
        }
        // epilogue: relu + dot with w2 segment
#pragma unroll
        for (int i = 0; i < 8; i++) {
#pragma unroll
            for (int j = 0; j < 8; j++) {
                int colc = col0 + tx * 8 + j;
                float v = fmaxf(acc[i][j] + b1[colc], 0.f);
                ga[i] = fmaf(v, w2[colc], ga[i]);
            }
        }
    }
    // reduce 16 partials per row
#pragma unroll
    for (int i = 0; i < 8; i++) gred[ty * 8 + i][tx] = ga[i];
    __syncthreads();
    if (tid < 128) {
        float s = 0.f;
#pragma unroll
        for (int j = 0; j < 16; j++) s += gred[tid][j];
        int row = row0 + tid;
        if (row < M) gate[row] = s + b2[0];
    }
}

// ---------------- GraphNorm stats (one pass, f32 accum from bf16) ----------------
__global__ __launch_bounds__(256) void k_stats(const ushort* __restrict__ y, const int* __restrict__ gstart,
                                               const float* __restrict__ alpha,
                                               float* __restrict__ mean, float* __restrict__ inv) {
    int g = blockIdx.x, t = threadIdx.x;
    int s = gstart[g], e = gstart[g + 1];
    float s1 = 0.f, s2 = 0.f;
    for (int i = s; i < e; i++) {
        float v = bf2f(y[(size_t)i * DIMH + t]);
        s1 += v; s2 = fmaf(v, v, s2);
    }
    float cnt = (float)((e - s) > 1 ? (e - s) : 1);
    float m = s1 / cnt;
    float a = alpha[t];
    float am = a * m;
    float var = s2 / cnt - 2.f * am * m + am * am;
    mean[(size_t)g * DIMH + t] = m;
    inv[(size_t)g * DIMH + t] = rsqrtf(var + EPSV);
}

// ---------------- norm + (relu) + residual, in-place into x (bf16) ----------------
__global__ __launch_bounds__(256) void k_norm(const ushort* __restrict__ y, const int* __restrict__ batch,
                                              const float* __restrict__ mean, const float* __restrict__ inv,
                                              const float* __restrict__ alpha, const float* __restrict__ gamma,
                                              const float* __restrict__ beta, ushort* __restrict__ x, int relu) {
    int gi = blockIdx.x * 256 + threadIdx.x;
    int node = gi >> 6, q = gi & 63;
    if (node >= NN) return;
    int b = batch[node];
    ushort4 yv = ((const ushort4*)y)[gi];
    ushort4 xv = ((const ushort4*)x)[gi];
    float vv[4] = { bf2f(yv.x), bf2f(yv.y), bf2f(yv.z), bf2f(yv.w) };
    float xo[4] = { bf2f(xv.x), bf2f(xv.y), bf2f(xv.z), bf2f(xv.w) };
#pragma unroll
    for (int c = 0; c < 4; c++) {
        int colc = q * 4 + c;
        float m  = mean[(size_t)b * DIMH + colc];
        float iv = inv[(size_t)b * DIMH + colc];
        float o = (vv[c] - alpha[colc] * m) * iv * gamma[colc] + beta[colc];
        if (relu) o = fmaxf(o, 0.f);
        xo[c] += o;
    }
    ushort4 o4; o4.x = f2bf(xo[0]); o4.y = f2bf(xo[1]); o4.z = f2bf(xo[2]); o4.w = f2bf(xo[3]);
    ((ushort4*)x)[gi] = o4;
}

// ---------------- segment softmax + weighted pool (x bf16) ----------------
__global__ __launch_bounds__(256) void k_pool(const ushort* __restrict__ x, const float* __restrict__ gate,
                                              const int* __restrict__ gstart, float* __restrict__ outg) {
    __shared__ float red[256];
    __shared__ float wbuf[256];
    int g = blockIdx.x, t = threadIdx.x;
    int s = gstart[g], e = gstart[g + 1];
    if (s >= e) { outg[(size_t)g * DIMH + t] = 0.f; return; }
    float m = -3.4e38f;
    for (int i = s + t; i < e; i += 256) m = fmaxf(m, gate[i]);
    red[t] = m; __syncthreads();
    for (int o = 128; o > 0; o >>= 1) { if (t < o) red[t] = fmaxf(red[t], red[t + o]); __syncthreads(); }
    m = red[0]; __syncthreads();
    float se = 0.f;
    for (int i = s + t; i < e; i += 256) se += expf(gate[i] - m);
    red[t] = se; __syncthreads();
    for (int o = 128; o > 0; o >>= 1) { if (t < o) red[t] += red[t + o]; __syncthreads(); }
    float inv_se = 1.f / red[0];
    float o_acc = 0.f;
    for (int base = s; base < e; base += 256) {
        __syncthreads();
        int i = base + t;
        wbuf[t] = (i < e) ? expf(gate[i] - m) * inv_se : 0.f;
        __syncthreads();
        int cnt = min(256, e - base);
        for (int j = 0; j < cnt; j++) o_acc += wbuf[j] * bf2f(x[(size_t)(base + j) * DIMH + t]);
    }
    outg[(size_t)g * DIMH + t] = o_acc;
}

__global__ __launch_bounds__(256) void k_final(float* __restrict__ out) {
    const int GD = GG * DIMH;
    int i = blockIdx.x * 256 + threadIdx.x;
    if (i >= GD) return;
    float s = out[i] + out[GD + i] + out[2 * GD + i] + out[3 * GD + i];
    out[4 * GD + i] = 0.25f * s;
}

__global__ __launch_bounds__(256) void k_zero_out(float* __restrict__ out, int n) {
    int i = blockIdx.x * 256 + threadIdx.x;
    if (i < n) out[i] = 0.f;
}

// ---------------- host ----------------
extern "C" void kernel_launch(void* const* d_in, const int* in_sizes, int n_in,
                              void* d_out, int out_size, void* d_ws, size_t ws_size,
                              hipStream_t stream) {
    const int*   x_idx     = (const int*)d_in[0];
    const int*   node_dep  = (const int*)d_in[1];
    const int*   eidx      = (const int*)d_in[2];
    const int*   batch     = (const int*)d_in[3];
    const float* emb_node  = (const float*)d_in[4];
    const float* emb_depth = (const float*)d_in[5];
    const float* gin_w1    = (const float*)d_in[6];
    const float* gin_b1    = (const float*)d_in[7];
    const float* gin_w2    = (const float*)d_in[8];
    const float* gin_b2    = (const float*)d_in[9];
    const float* gn_alpha  = (const float*)d_in[10];
    const float* gn_gamma  = (const float*)d_in[11];
    const float* gn_beta   = (const float*)d_in[12];
    const float* att_w1    = (const float*)d_in[13];
    const float* att_b1    = (const float*)d_in[14];
    const float* att_w2    = (const float*)d_in[15];
    const float* att_b2    = (const float*)d_in[16];
    float* out = (float*)d_out;
    (void)in_sizes; (void)n_in;

    // workspace plan (bf16 node tensors): ~163 MB
    const size_t SZ_NODE_BF16 = (size_t)NN * DIMH * 2;   // 51.2 MB
    size_t required = 3 * ((SZ_NODE_BF16 + 255) & ~(size_t)255)
                    + ((size_t)EE * 4 + 256) + ((size_t)(NN + 1) * 4 + 256) * 2
                    + 4096 + 8192 + 2 * ((size_t)GG * DIMH * 4 + 256) + ((size_t)NN * 4 + 256);
    if (ws_size < required) {   // diagnostic fallback: no crash, absmax = max|ref|
        k_zero_out<<<(out_size + 255) / 256, 256, 0, stream>>>(out, out_size);
        return;
    }

    char* w = (char*)d_ws;
    size_t off = 0;
    auto alloc = [&](size_t bytes) -> char* {
        char* p = w + off;
        off += (bytes + 255) & ~(size_t)255;
        return p;
    };
    ushort* x  = (ushort*)alloc(SZ_NODE_BF16);
    ushort* hb = (ushort*)alloc(SZ_NODE_BF16);   // h, then y2
    ushort* y1 = (ushort*)alloc(SZ_NODE_BF16);
    int* deg    = (int*)alloc((size_t)NN * 4);   // also cursor
    int* rs     = (int*)alloc((size_t)(NN + 1) * 4);
    int* part   = (int*)alloc(512 * 4);
    int* gstart = (int*)alloc((GG + 1) * 4);
    int* col    = (int*)alloc((size_t)EE * 4);
    float* mean = (float*)alloc((size_t)GG * DIMH * 4);
    float* inv  = (float*)alloc((size_t)GG * DIMH * 4);
    float* gate = (float*)alloc((size_t)NN * 4);

    const int* src  = eidx;
    const int* dstp = eidx + EE;

    hipMemsetAsync(deg, 0, (size_t)NN * 4, stream);
    k_graph_bounds<<<(GG + 1 + 255) / 256, 256, 0, stream>>>(batch, gstart);
    k_hist<<<(EE + 255) / 256, 256, 0, stream>>>(dstp, deg);
    int nb = (NN + 255) / 256;  // 391
    k_scan_a<<<nb, 256, 0, stream>>>(deg, rs, part);
    k_scan_b<<<1, 512, 0, stream>>>(part, nb, rs);
    k_scan_c<<<nb, 256, 0, stream>>>(rs, part);
    k_copy_int<<<nb, 256, 0, stream>>>(rs, deg, NN);   // cursor = row_start
    k_scatter<<<(EE + 255) / 256, 256, 0, stream>>>(src, dstp, deg, col);
    k_encoder<<<(NN * 64 + 255) / 256, 256, 0, stream>>>(x_idx, node_dep, emb_node, emb_depth, x);

    const int GD = GG * DIMH;
    for (int d = 0; d < NDEPTH; d++) {
        k_aggregate<<<(NN + 3) / 4, 256, 0, stream>>>(x, rs, col, hb);
        dim3 g1((NN + 127) / 128, 2);
        k_gemm<true ><<<g1, 256, 0, stream>>>(hb, gin_w1 + (size_t)d * 65536, gin_b1 + d * 256, y1, NN);
        k_gemm<false><<<g1, 256, 0, stream>>>(y1, gin_w2 + (size_t)d * 65536, gin_b2 + d * 256, hb, NN);
        k_stats<<<GG, 256, 0, stream>>>(hb, gstart, gn_alpha + d * 256, mean, inv);
        k_norm<<<(NN * 64 + 255) / 256, 256, 0, stream>>>(hb, batch, mean, inv, gn_alpha + d * 256,
                                                          gn_gamma + d * 256, gn_beta + d * 256, x,
                                                          (d < NDEPTH - 1) ? 1 : 0);
        k_attgate<<<(NN + 127) / 128, 256, 0, stream>>>(x, att_w1 + (size_t)d * 131072, att_b1 + d * 512,
                                                        att_w2 + d * 512, att_b2 + d, gate, NN);
        k_pool<<<GG, 256, 0, stream>>>(x, gate, gstart, out + (size_t)d * GD);
    }
    k_final<<<(GD + 255) / 256, 256, 0, stream>>>(out);
}

// Round 3
// 1904.066 us; speedup vs baseline: 2.1612x; 2.1612x over previous
//
#include <hip/hip_runtime.h>
#include <hip/hip_bf16.h>

#define NN 100000
#define EE 1600000
#define GG 1000
#define DIMH 256
#define NDEPTH 4
static constexpr float EPSV = 1e-5f;

typedef unsigned short ushort;
typedef __attribute__((ext_vector_type(8))) ushort ushort8v;
typedef __attribute__((ext_vector_type(8))) short short8v;
typedef __attribute__((ext_vector_type(4))) float f32x4;

__device__ __forceinline__ float bf2f(ushort u) {
    return __uint_as_float(((unsigned)u) << 16);
}
__device__ __forceinline__ ushort f2bf(float f) {
    unsigned u = __float_as_uint(f);
    unsigned r = u + 0x7FFFu + ((u >> 16) & 1u);   // RNE
    return (ushort)(r >> 16);
}

// ---------------- CSR build ----------------
__global__ __launch_bounds__(256) void k_graph_bounds(const int* __restrict__ batch, int* __restrict__ gstart) {
    int g = blockIdx.x * 256 + threadIdx.x;
    if (g > GG) return;
    int lo = 0, hi = NN;
    while (lo < hi) { int mid = (lo + hi) >> 1; if (batch[mid] < g) lo = mid + 1; else hi = mid; }
    gstart[g] = lo;
}

__global__ __launch_bounds__(256) void k_hist(const int* __restrict__ dst, int* __restrict__ deg) {
    int e = blockIdx.x * 256 + threadIdx.x;
    if (e < EE) atomicAdd(&deg[dst[e]], 1);
}

__global__ __launch_bounds__(256) void k_scan_a(const int* __restrict__ deg, int* __restrict__ rs, int* __restrict__ part) {
    __shared__ int s[256];
    int t = threadIdx.x;
    int i = blockIdx.x * 256 + t;
    int v = (i < NN) ? deg[i] : 0;
    s[t] = v; __syncthreads();
    for (int off = 1; off < 256; off <<= 1) {
        int u = (t >= off) ? s[t - off] : 0;
        __syncthreads();
        s[t] += u;
        __syncthreads();
    }
    if (i < NN) rs[i] = s[t] - v;
    if (t == 255) part[blockIdx.x] = s[255];
}

__global__ __launch_bounds__(512) void k_scan_b(int* __restrict__ part, int nb, int* __restrict__ rs) {
    __shared__ int s[512];
    int t = threadIdx.x;
    int v = (t < nb) ? part[t] : 0;
    s[t] = v; __syncthreads();
    for (int off = 1; off < 512; off <<= 1) {
        int u = (t >= off) ? s[t - off] : 0;
        __syncthreads();
        s[t] += u;
        __syncthreads();
    }
    if (t < nb) part[t] = s[t] - v;  // exclusive
    if (t == 0) rs[NN] = EE;
}

__global__ __launch_bounds__(256) void k_scan_c(int* __restrict__ rs, const int* __restrict__ part) {
    int i = blockIdx.x * 256 + threadIdx.x;
    if (i < NN) rs[i] += part[blockIdx.x];
}

__global__ __launch_bounds__(256) void k_copy_int(const int* __restrict__ a, int* __restrict__ b, int n) {
    int i = blockIdx.x * 256 + threadIdx.x;
    if (i < n) b[i] = a[i];
}

__global__ __launch_bounds__(256) void k_scatter(const int* __restrict__ src, const int* __restrict__ dst,
                                                 int* __restrict__ cursor, int* __restrict__ col) {
    int e = blockIdx.x * 256 + threadIdx.x;
    if (e >= EE) return;
    int d = dst[e];
    int pos = atomicAdd(&cursor[d], 1);
    col[pos] = src[e];
}

// ---------------- weight transpose + bf16 split: W[K][N] f32 -> Wt_hi/lo[N][K] bf16 ----------------
__global__ __launch_bounds__(256) void k_wtrans(const float* __restrict__ in, ushort* __restrict__ out_hi,
                                                ushort* __restrict__ out_lo, int K, int N) {
    int d = blockIdx.z;
    in  += (size_t)d * K * N;
    out_hi += (size_t)d * K * N;
    out_lo += (size_t)d * K * N;
    int n0 = blockIdx.x * 32, k0 = blockIdx.y * 32;
    int t = threadIdx.x;
    int tx = t & 31, ty = t >> 5;      // ty 0..7
    __shared__ float tile[32][33];
#pragma unroll
    for (int j = 0; j < 4; j++) tile[ty + 8 * j][tx] = in[(size_t)(k0 + ty + 8 * j) * N + n0 + tx];
    __syncthreads();
#pragma unroll
    for (int j = 0; j < 4; j++) {
        float f = tile[tx][ty + 8 * j];
        ushort hi = f2bf(f);
        float lo = f - bf2f(hi);
        size_t o = (size_t)(n0 + ty + 8 * j) * K + k0 + tx;
        out_hi[o] = hi;
        out_lo[o] = f2bf(lo);
    }
}

// ---------------- node encoder ----------------
__global__ __launch_bounds__(256) void k_encoder(const int* __restrict__ xidx, const int* __restrict__ ndep,
                                                 const float* __restrict__ en, const float* __restrict__ ed,
                                                 ushort* __restrict__ x) {
    int gi = blockIdx.x * 256 + threadIdx.x;     // = node*64 + q
    int node = gi >> 6, q = gi & 63;
    if (node >= NN) return;
    float4 va = ((const float4*)en)[(size_t)xidx[node] * 64 + q];
    float4 vb = ((const float4*)ed)[(size_t)ndep[node] * 64 + q];
    ushort4 o;
    o.x = f2bf(va.x + vb.x); o.y = f2bf(va.y + vb.y);
    o.z = f2bf(va.z + vb.z); o.w = f2bf(va.w + vb.w);
    ((ushort4*)x)[gi] = o;
}

// ---------------- GIN aggregate ----------------
__global__ __launch_bounds__(256) void k_aggregate(const ushort* __restrict__ x, const int* __restrict__ rs,
                                                   const int* __restrict__ col, ushort* __restrict__ hb) {
    int node = blockIdx.x * 4 + (threadIdx.x >> 6);
    int lane = threadIdx.x & 63;
    if (node >= NN) return;
    const ushort4* x4 = (const ushort4*)x;
    ushort4 sv = x4[(size_t)node * 64 + lane];
    float a0 = bf2f(sv.x), a1 = bf2f(sv.y), a2 = bf2f(sv.z), a3 = bf2f(sv.w);
    int s = rs[node], e = rs[node + 1];
    for (int j = s; j < e; j++) {
        int c = col[j];
        ushort4 v = x4[(size_t)c * 64 + lane];
        a0 += bf2f(v.x); a1 += bf2f(v.y); a2 += bf2f(v.z); a3 += bf2f(v.w);
    }
    ushort4 o; o.x = f2bf(a0); o.y = f2bf(a1); o.z = f2bf(a2); o.w = f2bf(a3);
    ((ushort4*)hb)[(size_t)node * 64 + lane] = o;
}

// ---------------- MFMA GEMM: C[M,CN] = act(A[M,256] @ (Whi+Wlo)^T + bias) ----------------
// MODE 0: bias, store bf16.  MODE 1: bias+relu, store bf16.
// MODE 2: attgate partial: per-row sum over this 128-col chunk of relu(acc+b1)*w2 -> partial[row][by*2+wc]
template<int MODE>
__global__ __launch_bounds__(256) void k_mfma_gemm(const ushort* __restrict__ A,
                                                   const ushort* __restrict__ Bhi,
                                                   const ushort* __restrict__ Blo,
                                                   const float* __restrict__ bias,
                                                   const float* __restrict__ w2,
                                                   ushort* __restrict__ C,
                                                   float* __restrict__ partial,
                                                   int M) {
    __shared__ __align__(16) ushort As[128 * 64];
    __shared__ __align__(16) ushort Bh[128 * 64];
    __shared__ __align__(16) ushort Bl[128 * 64];
    int t = threadIdx.x;
    int wv = t >> 6, l = t & 63;
    int wr = wv >> 1, wc = wv & 1;
    int row0 = blockIdx.x * 128;
    int col0 = blockIdx.y * 128;

    f32x4 acc[4][4];
#pragma unroll
    for (int m = 0; m < 4; m++)
#pragma unroll
        for (int n = 0; n < 4; n++) acc[m][n] = (f32x4){0.f, 0.f, 0.f, 0.f};

    // staging constants: issue i covers rows stripe*8 .. +8 (1KB each)
    int srow_in = l >> 3;       // 0..7
    int slot    = l & 7;        // 16B chunk slot within a 128B row

    for (int k0 = 0; k0 < 256; k0 += 64) {
#pragma unroll
        for (int i = 0; i < 4; i++) {
            int stripe = wv * 4 + i;                // 0..15
            int rl = stripe * 8 + srow_in;          // 0..127
            int gc = slot ^ (rl & 7);               // pre-swizzled global chunk
            const ushort* ga = A + (size_t)min(row0 + rl, M - 1) * 256 + k0 + gc * 8;
            __builtin_amdgcn_global_load_lds((const __attribute__((address_space(1))) void*)ga,
                                             (__attribute__((address_space(3))) void*)(As + stripe * 512),
                                             16, 0, 0);
            const ushort* gh = Bhi + (size_t)(col0 + rl) * 256 + k0 + gc * 8;
            __builtin_amdgcn_global_load_lds((const __attribute__((address_space(1))) void*)gh,
                                             (__attribute__((address_space(3))) void*)(Bh + stripe * 512),
                                             16, 0, 0);
            const ushort* gl = Blo + (size_t)(col0 + rl) * 256 + k0 + gc * 8;
            __builtin_amdgcn_global_load_lds((const __attribute__((address_space(1))) void*)gl,
                                             (__attribute__((address_space(3))) void*)(Bl + stripe * 512),
                                             16, 0, 0);
        }
        __syncthreads();
#pragma unroll
        for (int s = 0; s < 2; s++) {
            short8v af[4], bhf[4], blf[4];
#pragma unroll
            for (int m = 0; m < 4; m++) {
                int rl = wr * 64 + m * 16 + (l & 15);
                int ch = (s * 4 + (l >> 4)) ^ (rl & 7);
                af[m] = *(const short8v*)(As + rl * 64 + ch * 8);
            }
#pragma unroll
            for (int n = 0; n < 4; n++) {
                int rl = wc * 64 + n * 16 + (l & 15);
                int ch = (s * 4 + (l >> 4)) ^ (rl & 7);
                bhf[n] = *(const short8v*)(Bh + rl * 64 + ch * 8);
                blf[n] = *(const short8v*)(Bl + rl * 64 + ch * 8);
            }
#pragma unroll
            for (int m = 0; m < 4; m++)
#pragma unroll
                for (int n = 0; n < 4; n++) {
                    acc[m][n] = __builtin_amdgcn_mfma_f32_16x16x32_bf16(af[m], bhf[n], acc[m][n], 0, 0, 0);
                    acc[m][n] = __builtin_amdgcn_mfma_f32_16x16x32_bf16(af[m], blf[n], acc[m][n], 0, 0, 0);
                }
        }
        __syncthreads();
    }

    if (MODE == 2) {
        float b1v[4], w2v[4];
#pragma unroll
        for (int n = 0; n < 4; n++) {
            int colc = col0 + wc * 64 + n * 16 + (l & 15);
            b1v[n] = bias[colc];
            w2v[n] = w2[colc];
        }
#pragma unroll
        for (int m = 0; m < 4; m++) {
#pragma unroll
            for (int j = 0; j < 4; j++) {
                float p = 0.f;
#pragma unroll
                for (int n = 0; n < 4; n++) {
                    float v = fmaxf(acc[m][n][j] + b1v[n], 0.f);
                    p = fmaf(v, w2v[n], p);
                }
#pragma unroll
                for (int off = 1; off < 16; off <<= 1) p += __shfl_xor(p, off, 64);
                if ((l & 15) == 0) {
                    int row = row0 + wr * 64 + m * 16 + ((l >> 4) << 2) + j;
                    if (row < M) partial[(size_t)row * 8 + blockIdx.y * 2 + wc] = p;
                }
            }
        }
    } else {
        float bv[4];
#pragma unroll
        for (int n = 0; n < 4; n++) bv[n] = bias[col0 + wc * 64 + n * 16 + (l & 15)];
#pragma unroll
        for (int m = 0; m < 4; m++) {
#pragma unroll
            for (int j = 0; j < 4; j++) {
                int row = row0 + wr * 64 + m * 16 + ((l >> 4) << 2) + j;
                if (row < M) {
#pragma unroll
                    for (int n = 0; n < 4; n++) {
                        float v = acc[m][n][j] + bv[n];
                        if (MODE == 1) v = fmaxf(v, 0.f);
                        C[(size_t)row * 256 + col0 + wc * 64 + n * 16 + (l & 15)] = f2bf(v);
                    }
                }
            }
        }
    }
}

// ---------------- gate finisher ----------------
__global__ __launch_bounds__(256) void k_gatefin(const float* __restrict__ partial, const float* __restrict__ b2,
                                                 float* __restrict__ gate) {
    int i = blockIdx.x * 256 + threadIdx.x;
    if (i >= NN) return;
    const float4* p = (const float4*)(partial + (size_t)i * 8);
    float4 u = p[0], v = p[1];
    gate[i] = u.x + u.y + u.z + u.w + v.x + v.y + v.z + v.w + b2[0];
}

// ---------------- GraphNorm stats ----------------
__global__ __launch_bounds__(256) void k_stats(const ushort* __restrict__ y, const int* __restrict__ gstart,
                                               const float* __restrict__ alpha,
                                               float* __restrict__ mean, float* __restrict__ inv) {
    int g = blockIdx.x, t = threadIdx.x;
    int s = gstart[g], e = gstart[g + 1];
    float s1 = 0.f, s2 = 0.f;
    for (int i = s; i < e; i++) {
        float v = bf2f(y[(size_t)i * DIMH + t]);
        s1 += v; s2 = fmaf(v, v, s2);
    }
    float cnt = (float)((e - s) > 1 ? (e - s) : 1);
    float m = s1 / cnt;
    float a = alpha[t];
    float am = a * m;
    float var = s2 / cnt - 2.f * am * m + am * am;
    mean[(size_t)g * DIMH + t] = m;
    inv[(size_t)g * DIMH + t] = rsqrtf(var + EPSV);
}

// ---------------- norm + (relu) + residual ----------------
__global__ __launch_bounds__(256) void k_norm(const ushort* __restrict__ y, const int* __restrict__ batch,
                                              const float* __restrict__ mean, const float* __restrict__ inv,
                                              const float* __restrict__ alpha, const float* __restrict__ gamma,
                                              const float* __restrict__ beta, ushort* __restrict__ x, int relu) {
    int gi = blockIdx.x * 256 + threadIdx.x;
    int node = gi >> 6, q = gi & 63;
    if (node >= NN) return;
    int b = batch[node];
    ushort4 yv = ((const ushort4*)y)[gi];
    ushort4 xv = ((const ushort4*)x)[gi];
    float vv[4] = { bf2f(yv.x), bf2f(yv.y), bf2f(yv.z), bf2f(yv.w) };
    float xo[4] = { bf2f(xv.x), bf2f(xv.y), bf2f(xv.z), bf2f(xv.w) };
#pragma unroll
    for (int c = 0; c < 4; c++) {
        int colc = q * 4 + c;
        float m  = mean[(size_t)b * DIMH + colc];
        float iv = inv[(size_t)b * DIMH + colc];
        float o = (vv[c] - alpha[colc] * m) * iv * gamma[colc] + beta[colc];
        if (relu) o = fmaxf(o, 0.f);
        xo[c] += o;
    }
    ushort4 o4; o4.x = f2bf(xo[0]); o4.y = f2bf(xo[1]); o4.z = f2bf(xo[2]); o4.w = f2bf(xo[3]);
    ((ushort4*)x)[gi] = o4;
}

// ---------------- segment softmax + weighted pool ----------------
__global__ __launch_bounds__(256) void k_pool(const ushort* __restrict__ x, const float* __restrict__ gate,
                                              const int* __restrict__ gstart, float* __restrict__ outg) {
    __shared__ float red[256];
    __shared__ float wbuf[256];
    int g = blockIdx.x, t = threadIdx.x;
    int s = gstart[g], e = gstart[g + 1];
    if (s >= e) { outg[(size_t)g * DIMH + t] = 0.f; return; }
    float m = -3.4e38f;
    for (int i = s + t; i < e; i += 256) m = fmaxf(m, gate[i]);
    red[t] = m; __syncthreads();
    for (int o = 128; o > 0; o >>= 1) { if (t < o) red[t] = fmaxf(red[t], red[t + o]); __syncthreads(); }
    m = red[0]; __syncthreads();
    float se = 0.f;
    for (int i = s + t; i < e; i += 256) se += expf(gate[i] - m);
    red[t] = se; __syncthreads();
    for (int o = 128; o > 0; o >>= 1) { if (t < o) red[t] += red[t + o]; __syncthreads(); }
    float inv_se = 1.f / red[0];
    float o_acc = 0.f;
    for (int base = s; base < e; base += 256) {
        __syncthreads();
        int i = base + t;
        wbuf[t] = (i < e) ? expf(gate[i] - m) * inv_se : 0.f;
        __syncthreads();
        int cnt = min(256, e - base);
        for (int j = 0; j < cnt; j++) o_acc += wbuf[j] * bf2f(x[(size_t)(base + j) * DIMH + t]);
    }
    outg[(size_t)g * DIMH + t] = o_acc;
}

__global__ __launch_bounds__(256) void k_final(float* __restrict__ out) {
    const int GD = GG * DIMH;
    int i = blockIdx.x * 256 + threadIdx.x;
    if (i >= GD) return;
    float s = out[i] + out[GD + i] + out[2 * GD + i] + out[3 * GD + i];
    out[4 * GD + i] = 0.25f * s;
}

__global__ __launch_bounds__(256) void k_zero_out(float* __restrict__ out, int n) {
    int i = blockIdx.x * 256 + threadIdx.x;
    if (i < n) out[i] = 0.f;
}

// ---------------- host ----------------
extern "C" void kernel_launch(void* const* d_in, const int* in_sizes, int n_in,
                              void* d_out, int out_size, void* d_ws, size_t ws_size,
                              hipStream_t stream) {
    const int*   x_idx     = (const int*)d_in[0];
    const int*   node_dep  = (const int*)d_in[1];
    const int*   eidx      = (const int*)d_in[2];
    const int*   batch     = (const int*)d_in[3];
    const float* emb_node  = (const float*)d_in[4];
    const float* emb_depth = (const float*)d_in[5];
    const float* gin_w1    = (const float*)d_in[6];
    const float* gin_b1    = (const float*)d_in[7];
    const float* gin_w2    = (const float*)d_in[8];
    const float* gin_b2    = (const float*)d_in[9];
    const float* gn_alpha  = (const float*)d_in[10];
    const float* gn_gamma  = (const float*)d_in[11];
    const float* gn_beta   = (const float*)d_in[12];
    const float* att_w1    = (const float*)d_in[13];
    const float* att_b1    = (const float*)d_in[14];
    const float* att_w2    = (const float*)d_in[15];
    const float* att_b2    = (const float*)d_in[16];
    float* out = (float*)d_out;
    (void)in_sizes; (void)n_in;

    const size_t SZ_NODE_BF16 = (size_t)NN * DIMH * 2;   // 51.2 MB
    const size_t SZ_W256 = (size_t)NDEPTH * 256 * 256 * 2;  // 512 KB
    const size_t SZ_W512 = (size_t)NDEPTH * 256 * 512 * 2;  // 1 MB
    size_t required = 3 * ((SZ_NODE_BF16 + 255) & ~(size_t)255)
                    + 4 * SZ_W256 + 2 * SZ_W512
                    + ((size_t)EE * 4 + 256) + ((size_t)(NN + 1) * 4 + 256) * 2
                    + 4096 + 8192 + 2 * ((size_t)GG * DIMH * 4 + 256) + ((size_t)NN * 4 + 256) + 65536;
    if (ws_size < required) {
        k_zero_out<<<(out_size + 255) / 256, 256, 0, stream>>>(out, out_size);
        return;
    }

    char* w = (char*)d_ws;
    size_t off = 0;
    auto alloc = [&](size_t bytes) -> char* {
        char* p = w + off;
        off += (bytes + 255) & ~(size_t)255;
        return p;
    };
    ushort* x  = (ushort*)alloc(SZ_NODE_BF16);
    ushort* hb = (ushort*)alloc(SZ_NODE_BF16);   // h, then y2
    ushort* y1 = (ushort*)alloc(SZ_NODE_BF16);   // y1; reused as attgate partial f32 [N][8]
    float* partial = (float*)y1;
    ushort* wt_g1h = (ushort*)alloc(SZ_W256);
    ushort* wt_g1l = (ushort*)alloc(SZ_W256);
    ushort* wt_g2h = (ushort*)alloc(SZ_W256);
    ushort* wt_g2l = (ushort*)alloc(SZ_W256);
    ushort* wt_a1h = (ushort*)alloc(SZ_W512);
    ushort* wt_a1l = (ushort*)alloc(SZ_W512);
    int* deg    = (int*)alloc((size_t)NN * 4);   // also cursor
    int* rs     = (int*)alloc((size_t)(NN + 1) * 4);
    int* part   = (int*)alloc(512 * 4);
    int* gstart = (int*)alloc((GG + 1) * 4);
    int* col    = (int*)alloc((size_t)EE * 4);
    float* mean = (float*)alloc((size_t)GG * DIMH * 4);
    float* inv  = (float*)alloc((size_t)GG * DIMH * 4);
    float* gate = (float*)alloc((size_t)NN * 4);

    const int* src  = eidx;
    const int* dstp = eidx + EE;

    hipMemsetAsync(deg, 0, (size_t)NN * 4, stream);
    k_graph_bounds<<<(GG + 1 + 255) / 256, 256, 0, stream>>>(batch, gstart);
    k_hist<<<(EE + 255) / 256, 256, 0, stream>>>(dstp, deg);
    int nb = (NN + 255) / 256;
    k_scan_a<<<nb, 256, 0, stream>>>(deg, rs, part);
    k_scan_b<<<1, 512, 0, stream>>>(part, nb, rs);
    k_scan_c<<<nb, 256, 0, stream>>>(rs, part);
    k_copy_int<<<nb, 256, 0, stream>>>(rs, deg, NN);
    k_scatter<<<(EE + 255) / 256, 256, 0, stream>>>(src, dstp, deg, col);
    k_encoder<<<(NN * 64 + 255) / 256, 256, 0, stream>>>(x_idx, node_dep, emb_node, emb_depth, x);

    // weight prep: transpose + hi/lo bf16 split
    k_wtrans<<<dim3(8, 8, NDEPTH), 256, 0, stream>>>(gin_w1, wt_g1h, wt_g1l, 256, 256);
    k_wtrans<<<dim3(8, 8, NDEPTH), 256, 0, stream>>>(gin_w2, wt_g2h, wt_g2l, 256, 256);
    k_wtrans<<<dim3(16, 8, NDEPTH), 256, 0, stream>>>(att_w1, wt_a1h, wt_a1l, 256, 512);

    const int GD = GG * DIMH;
    const int MB = (NN + 127) / 128;   // 782
    for (int d = 0; d < NDEPTH; d++) {
        k_aggregate<<<(NN + 3) / 4, 256, 0, stream>>>(x, rs, col, hb);
        k_mfma_gemm<1><<<dim3(MB, 2), 256, 0, stream>>>(hb, wt_g1h + (size_t)d * 65536, wt_g1l + (size_t)d * 65536,
                                                        gin_b1 + d * 256, nullptr, y1, nullptr, NN);
        k_mfma_gemm<0><<<dim3(MB, 2), 256, 0, stream>>>(y1, wt_g2h + (size_t)d * 65536, wt_g2l + (size_t)d * 65536,
                                                        gin_b2 + d * 256, nullptr, hb, nullptr, NN);
        k_stats<<<GG, 256, 0, stream>>>(hb, gstart, gn_alpha + d * 256, mean, inv);
        k_norm<<<(NN * 64 + 255) / 256, 256, 0, stream>>>(hb, batch, mean, inv, gn_alpha + d * 256,
                                                          gn_gamma + d * 256, gn_beta + d * 256, x,
                                                          (d < NDEPTH - 1) ? 1 : 0);
        k_mfma_gemm<2><<<dim3(MB, 4), 256, 0, stream>>>(x, wt_a1h + (size_t)d * 131072, wt_a1l + (size_t)d * 131072,
                                                        att_b1 + d * 512, att_w2 + d * 512, nullptr, partial, NN);
        k_gatefin<<<(NN + 255) / 256, 256, 0, stream>>>(partial, att_b2 + d, gate);
        k_pool<<<GG, 256, 0, stream>>>(x, gate, gstart, out + (size_t)d * GD);
    }
    k_final<<<(GD + 255) / 256, 256, 0, stream>>>(out);
}

// Round 4
// 1631.891 us; speedup vs baseline: 2.5217x; 1.1668x over previous
//
#include <hip/hip_runtime.h>
#include <hip/hip_bf16.h>

#define NN 100000
#define EE 1600000
#define GG 1000
#define DIMH 256
#define NDEPTH 4
static constexpr float EPSV = 1e-5f;

typedef unsigned short ushort;
typedef __attribute__((ext_vector_type(8))) ushort ushort8v;
typedef __attribute__((ext_vector_type(8))) short short8v;
typedef __attribute__((ext_vector_type(4))) float f32x4;

__device__ __forceinline__ float bf2f(ushort u) {
    return __uint_as_float(((unsigned)u) << 16);
}
__device__ __forceinline__ ushort f2bf(float f) {
    unsigned u = __float_as_uint(f);
    unsigned r = u + 0x7FFFu + ((u >> 16) & 1u);   // RNE
    return (ushort)(r >> 16);
}

// ---------------- CSR build ----------------
__global__ __launch_bounds__(256) void k_graph_bounds(const int* __restrict__ batch, int* __restrict__ gstart) {
    int g = blockIdx.x * 256 + threadIdx.x;
    if (g > GG) return;
    int lo = 0, hi = NN;
    while (lo < hi) { int mid = (lo + hi) >> 1; if (batch[mid] < g) lo = mid + 1; else hi = mid; }
    gstart[g] = lo;
}

__global__ __launch_bounds__(256) void k_hist(const int* __restrict__ dst, int* __restrict__ deg) {
    int e = blockIdx.x * 256 + threadIdx.x;
    if (e < EE) atomicAdd(&deg[dst[e]], 1);
}

__global__ __launch_bounds__(256) void k_scan_a(const int* __restrict__ deg, int* __restrict__ rs, int* __restrict__ part) {
    __shared__ int s[256];
    int t = threadIdx.x;
    int i = blockIdx.x * 256 + t;
    int v = (i < NN) ? deg[i] : 0;
    s[t] = v; __syncthreads();
    for (int off = 1; off < 256; off <<= 1) {
        int u = (t >= off) ? s[t - off] : 0;
        __syncthreads();
        s[t] += u;
        __syncthreads();
    }
    if (i < NN) rs[i] = s[t] - v;
    if (t == 255) part[blockIdx.x] = s[255];
}

__global__ __launch_bounds__(512) void k_scan_b(int* __restrict__ part, int nb, int* __restrict__ rs) {
    __shared__ int s[512];
    int t = threadIdx.x;
    int v = (t < nb) ? part[t] : 0;
    s[t] = v; __syncthreads();
    for (int off = 1; off < 512; off <<= 1) {
        int u = (t >= off) ? s[t - off] : 0;
        __syncthreads();
        s[t] += u;
        __syncthreads();
    }
    if (t < nb) part[t] = s[t] - v;  // exclusive
    if (t == 0) rs[NN] = EE;
}

__global__ __launch_bounds__(256) void k_scan_c(int* __restrict__ rs, const int* __restrict__ part) {
    int i = blockIdx.x * 256 + threadIdx.x;
    if (i < NN) rs[i] += part[blockIdx.x];
}

__global__ __launch_bounds__(256) void k_copy_int(const int* __restrict__ a, int* __restrict__ b, int n) {
    int i = blockIdx.x * 256 + threadIdx.x;
    if (i < n) b[i] = a[i];
}

__global__ __launch_bounds__(256) void k_scatter(const int* __restrict__ src, const int* __restrict__ dst,
                                                 int* __restrict__ cursor, int* __restrict__ col) {
    int e = blockIdx.x * 256 + threadIdx.x;
    if (e >= EE) return;
    int d = dst[e];
    int pos = atomicAdd(&cursor[d], 1);
    col[pos] = src[e];
}

// ---------------- weight transpose + bf16 split: W[K][N] f32 -> Wt_hi/lo[N][K] bf16 ----------------
__global__ __launch_bounds__(256) void k_wtrans(const float* __restrict__ in, ushort* __restrict__ out_hi,
                                                ushort* __restrict__ out_lo, int K, int N) {
    int d = blockIdx.z;
    in  += (size_t)d * K * N;
    out_hi += (size_t)d * K * N;
    out_lo += (size_t)d * K * N;
    int n0 = blockIdx.x * 32, k0 = blockIdx.y * 32;
    int t = threadIdx.x;
    int tx = t & 31, ty = t >> 5;      // ty 0..7
    __shared__ float tile[32][33];
#pragma unroll
    for (int j = 0; j < 4; j++) tile[ty + 8 * j][tx] = in[(size_t)(k0 + ty + 8 * j) * N + n0 + tx];
    __syncthreads();
#pragma unroll
    for (int j = 0; j < 4; j++) {
        float f = tile[tx][ty + 8 * j];
        ushort hi = f2bf(f);
        float lo = f - bf2f(hi);
        size_t o = (size_t)(n0 + ty + 8 * j) * K + k0 + tx;
        out_hi[o] = hi;
        out_lo[o] = f2bf(lo);
    }
}

// ---------------- node encoder ----------------
__global__ __launch_bounds__(256) void k_encoder(const int* __restrict__ xidx, const int* __restrict__ ndep,
                                                 const float* __restrict__ en, const float* __restrict__ ed,
                                                 ushort* __restrict__ x) {
    int gi = blockIdx.x * 256 + threadIdx.x;     // = node*64 + q
    int node = gi >> 6, q = gi & 63;
    if (node >= NN) return;
    float4 va = ((const float4*)en)[(size_t)xidx[node] * 64 + q];
    float4 vb = ((const float4*)ed)[(size_t)ndep[node] * 64 + q];
    ushort4 o;
    o.x = f2bf(va.x + vb.x); o.y = f2bf(va.y + vb.y);
    o.z = f2bf(va.z + vb.z); o.w = f2bf(va.w + vb.w);
    ((ushort4*)x)[gi] = o;
}

// ---------------- GIN aggregate (4x unrolled, 4 load chains in flight) ----------------
__global__ __launch_bounds__(256) void k_aggregate(const ushort* __restrict__ x, const int* __restrict__ rs,
                                                   const int* __restrict__ col, ushort* __restrict__ hb) {
    int node = blockIdx.x * 4 + (threadIdx.x >> 6);
    int lane = threadIdx.x & 63;
    if (node >= NN) return;
    const ushort4* x4 = (const ushort4*)x;
    ushort4 sv = x4[(size_t)node * 64 + lane];
    float a0 = bf2f(sv.x), a1 = bf2f(sv.y), a2 = bf2f(sv.z), a3 = bf2f(sv.w);
    float b0 = 0.f, b1 = 0.f, b2 = 0.f, b3 = 0.f;
    float c0 = 0.f, c1 = 0.f, c2 = 0.f, c3 = 0.f;
    float d0 = 0.f, d1 = 0.f, d2 = 0.f, d3 = 0.f;
    int s = rs[node], e = rs[node + 1];
    int j = s;
    for (; j + 4 <= e; j += 4) {
        int i0 = col[j], i1 = col[j + 1], i2 = col[j + 2], i3 = col[j + 3];
        ushort4 v0 = x4[(size_t)i0 * 64 + lane];
        ushort4 v1 = x4[(size_t)i1 * 64 + lane];
        ushort4 v2 = x4[(size_t)i2 * 64 + lane];
        ushort4 v3 = x4[(size_t)i3 * 64 + lane];
        a0 += bf2f(v0.x); a1 += bf2f(v0.y); a2 += bf2f(v0.z); a3 += bf2f(v0.w);
        b0 += bf2f(v1.x); b1 += bf2f(v1.y); b2 += bf2f(v1.z); b3 += bf2f(v1.w);
        c0 += bf2f(v2.x); c1 += bf2f(v2.y); c2 += bf2f(v2.z); c3 += bf2f(v2.w);
        d0 += bf2f(v3.x); d1 += bf2f(v3.y); d2 += bf2f(v3.z); d3 += bf2f(v3.w);
    }
    for (; j < e; j++) {
        int c = col[j];
        ushort4 v = x4[(size_t)c * 64 + lane];
        a0 += bf2f(v.x); a1 += bf2f(v.y); a2 += bf2f(v.z); a3 += bf2f(v.w);
    }
    a0 += b0 + c0 + d0; a1 += b1 + c1 + d1; a2 += b2 + c2 + d2; a3 += b3 + c3 + d3;
    ushort4 o; o.x = f2bf(a0); o.y = f2bf(a1); o.z = f2bf(a2); o.w = f2bf(a3);
    ((ushort4*)hb)[(size_t)node * 64 + lane] = o;
}

// ---------------- MFMA GEMM: block 256x128, 4 waves of 128x64 (8x4 frags) ----------------
// MODE 0: bias, store bf16.  MODE 1: bias+relu, store bf16.
// MODE 2: attgate partial: per-row sum over this 128-col chunk of relu(acc+b1)*w2 -> partial[row][by*2+wc]
template<int MODE>
__global__ __launch_bounds__(256, 2) void k_mfma_gemm(const ushort* __restrict__ A,
                                                      const ushort* __restrict__ Bhi,
                                                      const ushort* __restrict__ Blo,
                                                      const float* __restrict__ bias,
                                                      const float* __restrict__ w2,
                                                      ushort* __restrict__ C,
                                                      float* __restrict__ partial,
                                                      int M) {
    __shared__ __align__(16) ushort As[256 * 64];   // 32 KB
    __shared__ __align__(16) ushort Bh[128 * 64];   // 16 KB
    __shared__ __align__(16) ushort Bl[128 * 64];   // 16 KB
    int t = threadIdx.x;
    int wv = t >> 6, l = t & 63;
    int wr = wv >> 1, wc = wv & 1;
    int row0 = blockIdx.x * 256;
    int col0 = blockIdx.y * 128;

    f32x4 acc[8][4];
#pragma unroll
    for (int m = 0; m < 8; m++)
#pragma unroll
        for (int n = 0; n < 4; n++) acc[m][n] = (f32x4){0.f, 0.f, 0.f, 0.f};

    int srow_in = l >> 3;       // 0..7
    int slot    = l & 7;        // 16B chunk slot within a 128B row

    for (int k0 = 0; k0 < 256; k0 += 64) {
        // A: 32 stripes of 8 rows (256 rows); 8 stripes per wave
#pragma unroll
        for (int i = 0; i < 8; i++) {
            int stripe = wv * 8 + i;                // 0..31
            int rl = stripe * 8 + srow_in;          // 0..255
            int gc = slot ^ (rl & 7);               // pre-swizzled global chunk
            const ushort* ga = A + (size_t)min(row0 + rl, M - 1) * 256 + k0 + gc * 8;
            __builtin_amdgcn_global_load_lds((const __attribute__((address_space(1))) void*)ga,
                                             (__attribute__((address_space(3))) void*)(As + stripe * 512),
                                             16, 0, 0);
        }
        // B: 16 stripes each plane; 4 per wave per plane
#pragma unroll
        for (int i = 0; i < 4; i++) {
            int stripe = wv * 4 + i;                // 0..15
            int rl = stripe * 8 + srow_in;          // 0..127
            int gc = slot ^ (rl & 7);
            const ushort* gh = Bhi + (size_t)(col0 + rl) * 256 + k0 + gc * 8;
            __builtin_amdgcn_global_load_lds((const __attribute__((address_space(1))) void*)gh,
                                             (__attribute__((address_space(3))) void*)(Bh + stripe * 512),
                                             16, 0, 0);
            const ushort* gl = Blo + (size_t)(col0 + rl) * 256 + k0 + gc * 8;
            __builtin_amdgcn_global_load_lds((const __attribute__((address_space(1))) void*)gl,
                                             (__attribute__((address_space(3))) void*)(Bl + stripe * 512),
                                             16, 0, 0);
        }
        __syncthreads();
#pragma unroll
        for (int s = 0; s < 2; s++) {
            short8v af[8], bhf[4], blf[4];
#pragma unroll
            for (int m = 0; m < 8; m++) {
                int rl = wr * 128 + m * 16 + (l & 15);
                int ch = (s * 4 + (l >> 4)) ^ (rl & 7);
                af[m] = *(const short8v*)(As + rl * 64 + ch * 8);
            }
#pragma unroll
            for (int n = 0; n < 4; n++) {
                int rl = wc * 64 + n * 16 + (l & 15);
                int ch = (s * 4 + (l >> 4)) ^ (rl & 7);
                bhf[n] = *(const short8v*)(Bh + rl * 64 + ch * 8);
                blf[n] = *(const short8v*)(Bl + rl * 64 + ch * 8);
            }
#pragma unroll
            for (int m = 0; m < 8; m++)
#pragma unroll
                for (int n = 0; n < 4; n++) {
                    acc[m][n] = __builtin_amdgcn_mfma_f32_16x16x32_bf16(af[m], bhf[n], acc[m][n], 0, 0, 0);
                    acc[m][n] = __builtin_amdgcn_mfma_f32_16x16x32_bf16(af[m], blf[n], acc[m][n], 0, 0, 0);
                }
        }
        __syncthreads();
    }

    if (MODE == 2) {
        float b1v[4], w2v[4];
#pragma unroll
        for (int n = 0; n < 4; n++) {
            int colc = col0 + wc * 64 + n * 16 + (l & 15);
            b1v[n] = bias[colc];
            w2v[n] = w2[colc];
        }
#pragma unroll
        for (int m = 0; m < 8; m++) {
#pragma unroll
            for (int j = 0; j < 4; j++) {
                float p = 0.f;
#pragma unroll
                for (int n = 0; n < 4; n++) {
                    float v = fmaxf(acc[m][n][j] + b1v[n], 0.f);
                    p = fmaf(v, w2v[n], p);
                }
#pragma unroll
                for (int off = 1; off < 16; off <<= 1) p += __shfl_xor(p, off, 64);
                if ((l & 15) == 0) {
                    int row = row0 + wr * 128 + m * 16 + ((l >> 4) << 2) + j;
                    if (row < M) partial[(size_t)row * 8 + blockIdx.y * 2 + wc] = p;
                }
            }
        }
    } else {
        float bv[4];
#pragma unroll
        for (int n = 0; n < 4; n++) bv[n] = bias[col0 + wc * 64 + n * 16 + (l & 15)];
#pragma unroll
        for (int m = 0; m < 8; m++) {
#pragma unroll
            for (int j = 0; j < 4; j++) {
                int row = row0 + wr * 128 + m * 16 + ((l >> 4) << 2) + j;
                if (row < M) {
#pragma unroll
                    for (int n = 0; n < 4; n++) {
                        float v = acc[m][n][j] + bv[n];
                        if (MODE == 1) v = fmaxf(v, 0.f);
                        C[(size_t)row * 256 + col0 + wc * 64 + n * 16 + (l & 15)] = f2bf(v);
                    }
                }
            }
        }
    }
}

// ---------------- gate finisher ----------------
__global__ __launch_bounds__(256) void k_gatefin(const float* __restrict__ partial, const float* __restrict__ b2,
                                                 float* __restrict__ gate) {
    int i = blockIdx.x * 256 + threadIdx.x;
    if (i >= NN) return;
    const float4* p = (const float4*)(partial + (size_t)i * 8);
    float4 u = p[0], v = p[1];
    gate[i] = u.x + u.y + u.z + u.w + v.x + v.y + v.z + v.w + b2[0];
}

// ---------------- GraphNorm stats ----------------
__global__ __launch_bounds__(256) void k_stats(const ushort* __restrict__ y, const int* __restrict__ gstart,
                                               const float* __restrict__ alpha,
                                               float* __restrict__ mean, float* __restrict__ inv) {
    int g = blockIdx.x, t = threadIdx.x;
    int s = gstart[g], e = gstart[g + 1];
    float s1 = 0.f, s2 = 0.f;
    for (int i = s; i < e; i++) {
        float v = bf2f(y[(size_t)i * DIMH + t]);
        s1 += v; s2 = fmaf(v, v, s2);
    }
    float cnt = (float)((e - s) > 1 ? (e - s) : 1);
    float m = s1 / cnt;
    float a = alpha[t];
    float am = a * m;
    float var = s2 / cnt - 2.f * am * m + am * am;
    mean[(size_t)g * DIMH + t] = m;
    inv[(size_t)g * DIMH + t] = rsqrtf(var + EPSV);
}

// ---------------- norm + (relu) + residual ----------------
__global__ __launch_bounds__(256) void k_norm(const ushort* __restrict__ y, const int* __restrict__ batch,
                                              const float* __restrict__ mean, const float* __restrict__ inv,
                                              const float* __restrict__ alpha, const float* __restrict__ gamma,
                                              const float* __restrict__ beta, ushort* __restrict__ x, int relu) {
    int gi = blockIdx.x * 256 + threadIdx.x;
    int node = gi >> 6, q = gi & 63;
    if (node >= NN) return;
    int b = batch[node];
    ushort4 yv = ((const ushort4*)y)[gi];
    ushort4 xv = ((const ushort4*)x)[gi];
    float vv[4] = { bf2f(yv.x), bf2f(yv.y), bf2f(yv.z), bf2f(yv.w) };
    float xo[4] = { bf2f(xv.x), bf2f(xv.y), bf2f(xv.z), bf2f(xv.w) };
#pragma unroll
    for (int c = 0; c < 4; c++) {
        int colc = q * 4 + c;
        float m  = mean[(size_t)b * DIMH + colc];
        float iv = inv[(size_t)b * DIMH + colc];
        float o = (vv[c] - alpha[colc] * m) * iv * gamma[colc] + beta[colc];
        if (relu) o = fmaxf(o, 0.f);
        xo[c] += o;
    }
    ushort4 o4; o4.x = f2bf(xo[0]); o4.y = f2bf(xo[1]); o4.z = f2bf(xo[2]); o4.w = f2bf(xo[3]);
    ((ushort4*)x)[gi] = o4;
}

// ---------------- segment softmax + weighted pool ----------------
__global__ __launch_bounds__(256) void k_pool(const ushort* __restrict__ x, const float* __restrict__ gate,
                                              const int* __restrict__ gstart, float* __restrict__ outg) {
    __shared__ float red[256];
    __shared__ float wbuf[256];
    int g = blockIdx.x, t = threadIdx.x;
    int s = gstart[g], e = gstart[g + 1];
    if (s >= e) { outg[(size_t)g * DIMH + t] = 0.f; return; }
    float m = -3.4e38f;
    for (int i = s + t; i < e; i += 256) m = fmaxf(m, gate[i]);
    red[t] = m; __syncthreads();
    for (int o = 128; o > 0; o >>= 1) { if (t < o) red[t] = fmaxf(red[t], red[t + o]); __syncthreads(); }
    m = red[0]; __syncthreads();
    float se = 0.f;
    for (int i = s + t; i < e; i += 256) se += expf(gate[i] - m);
    red[t] = se; __syncthreads();
    for (int o = 128; o > 0; o >>= 1) { if (t < o) red[t] += red[t + o]; __syncthreads(); }
    float inv_se = 1.f / red[0];
    float o_acc = 0.f;
    for (int base = s; base < e; base += 256) {
        __syncthreads();
        int i = base + t;
        wbuf[t] = (i < e) ? expf(gate[i] - m) * inv_se : 0.f;
        __syncthreads();
        int cnt = min(256, e - base);
        for (int j = 0; j < cnt; j++) o_acc += wbuf[j] * bf2f(x[(size_t)(base + j) * DIMH + t]);
    }
    outg[(size_t)g * DIMH + t] = o_acc;
}

__global__ __launch_bounds__(256) void k_final(float* __restrict__ out) {
    const int GD = GG * DIMH;
    int i = blockIdx.x * 256 + threadIdx.x;
    if (i >= GD) return;
    float s = out[i] + out[GD + i] + out[2 * GD + i] + out[3 * GD + i];
    out[4 * GD + i] = 0.25f * s;
}

__global__ __launch_bounds__(256) void k_zero_out(float* __restrict__ out, int n) {
    int i = blockIdx.x * 256 + threadIdx.x;
    if (i < n) out[i] = 0.f;
}

// ---------------- host ----------------
extern "C" void kernel_launch(void* const* d_in, const int* in_sizes, int n_in,
                              void* d_out, int out_size, void* d_ws, size_t ws_size,
                              hipStream_t stream) {
    const int*   x_idx     = (const int*)d_in[0];
    const int*   node_dep  = (const int*)d_in[1];
    const int*   eidx      = (const int*)d_in[2];
    const int*   batch     = (const int*)d_in[3];
    const float* emb_node  = (const float*)d_in[4];
    const float* emb_depth = (const float*)d_in[5];
    const float* gin_w1    = (const float*)d_in[6];
    const float* gin_b1    = (const float*)d_in[7];
    const float* gin_w2    = (const float*)d_in[8];
    const float* gin_b2    = (const float*)d_in[9];
    const float* gn_alpha  = (const float*)d_in[10];
    const float* gn_gamma  = (const float*)d_in[11];
    const float* gn_beta   = (const float*)d_in[12];
    const float* att_w1    = (const float*)d_in[13];
    const float* att_b1    = (const float*)d_in[14];
    const float* att_w2    = (const float*)d_in[15];
    const float* att_b2    = (const float*)d_in[16];
    float* out = (float*)d_out;
    (void)in_sizes; (void)n_in;

    const size_t SZ_NODE_BF16 = (size_t)NN * DIMH * 2;   // 51.2 MB
    const size_t SZ_W256 = (size_t)NDEPTH * 256 * 256 * 2;  // 512 KB
    const size_t SZ_W512 = (size_t)NDEPTH * 256 * 512 * 2;  // 1 MB
    size_t required = 3 * ((SZ_NODE_BF16 + 255) & ~(size_t)255)
                    + 4 * SZ_W256 + 2 * SZ_W512
                    + ((size_t)EE * 4 + 256) + ((size_t)(NN + 1) * 4 + 256) * 2
                    + 4096 + 8192 + 2 * ((size_t)GG * DIMH * 4 + 256) + ((size_t)NN * 4 + 256) + 65536;
    if (ws_size < required) {
        k_zero_out<<<(out_size + 255) / 256, 256, 0, stream>>>(out, out_size);
        return;
    }

    char* w = (char*)d_ws;
    size_t off = 0;
    auto alloc = [&](size_t bytes) -> char* {
        char* p = w + off;
        off += (bytes + 255) & ~(size_t)255;
        return p;
    };
    ushort* x  = (ushort*)alloc(SZ_NODE_BF16);
    ushort* hb = (ushort*)alloc(SZ_NODE_BF16);   // h, then y2
    ushort* y1 = (ushort*)alloc(SZ_NODE_BF16);   // y1; reused as attgate partial f32 [N][8]
    float* partial = (float*)y1;
    ushort* wt_g1h = (ushort*)alloc(SZ_W256);
    ushort* wt_g1l = (ushort*)alloc(SZ_W256);
    ushort* wt_g2h = (ushort*)alloc(SZ_W256);
    ushort* wt_g2l = (ushort*)alloc(SZ_W256);
    ushort* wt_a1h = (ushort*)alloc(SZ_W512);
    ushort* wt_a1l = (ushort*)alloc(SZ_W512);
    int* deg    = (int*)alloc((size_t)NN * 4);   // also cursor
    int* rs     = (int*)alloc((size_t)(NN + 1) * 4);
    int* part   = (int*)alloc(512 * 4);
    int* gstart = (int*)alloc((GG + 1) * 4);
    int* col    = (int*)alloc((size_t)EE * 4);
    float* mean = (float*)alloc((size_t)GG * DIMH * 4);
    float* inv  = (float*)alloc((size_t)GG * DIMH * 4);
    float* gate = (float*)alloc((size_t)NN * 4);

    const int* src  = eidx;
    const int* dstp = eidx + EE;

    hipMemsetAsync(deg, 0, (size_t)NN * 4, stream);
    k_graph_bounds<<<(GG + 1 + 255) / 256, 256, 0, stream>>>(batch, gstart);
    k_hist<<<(EE + 255) / 256, 256, 0, stream>>>(dstp, deg);
    int nb = (NN + 255) / 256;
    k_scan_a<<<nb, 256, 0, stream>>>(deg, rs, part);
    k_scan_b<<<1, 512, 0, stream>>>(part, nb, rs);
    k_scan_c<<<nb, 256, 0, stream>>>(rs, part);
    k_copy_int<<<nb, 256, 0, stream>>>(rs, deg, NN);
    k_scatter<<<(EE + 255) / 256, 256, 0, stream>>>(src, dstp, deg, col);
    k_encoder<<<(NN * 64 + 255) / 256, 256, 0, stream>>>(x_idx, node_dep, emb_node, emb_depth, x);

    // weight prep: transpose + hi/lo bf16 split
    k_wtrans<<<dim3(8, 8, NDEPTH), 256, 0, stream>>>(gin_w1, wt_g1h, wt_g1l, 256, 256);
    k_wtrans<<<dim3(8, 8, NDEPTH), 256, 0, stream>>>(gin_w2, wt_g2h, wt_g2l, 256, 256);
    k_wtrans<<<dim3(16, 8, NDEPTH), 256, 0, stream>>>(att_w1, wt_a1h, wt_a1l, 256, 512);

    const int GD = GG * DIMH;
    const int MB = (NN + 255) / 256;   // 391
    for (int d = 0; d < NDEPTH; d++) {
        k_aggregate<<<(NN + 3) / 4, 256, 0, stream>>>(x, rs, col, hb);
        k_mfma_gemm<1><<<dim3(MB, 2), 256, 0, stream>>>(hb, wt_g1h + (size_t)d * 65536, wt_g1l + (size_t)d * 65536,
                                                        gin_b1 + d * 256, nullptr, y1, nullptr, NN);
        k_mfma_gemm<0><<<dim3(MB, 2), 256, 0, stream>>>(y1, wt_g2h + (size_t)d * 65536, wt_g2l + (size_t)d * 65536,
                                                        gin_b2 + d * 256, nullptr, hb, nullptr, NN);
        k_stats<<<GG, 256, 0, stream>>>(hb, gstart, gn_alpha + d * 256, mean, inv);
        k_norm<<<(NN * 64 + 255) / 256, 256, 0, stream>>>(hb, batch, mean, inv, gn_alpha + d * 256,
                                                          gn_gamma + d * 256, gn_beta + d * 256, x,
                                                          (d < NDEPTH - 1) ? 1 : 0);
        k_mfma_gemm<2><<<dim3(MB, 4), 256, 0, stream>>>(x, wt_a1h + (size_t)d * 131072, wt_a1l + (size_t)d * 131072,
                                                        att_b1 + d * 512, att_w2 + d * 512, nullptr, partial, NN);
        k_gatefin<<<(NN + 255) / 256, 256, 0, stream>>>(partial, att_b2 + d, gate);
        k_pool<<<GG, 256, 0, stream>>>(x, gate, gstart, out + (size_t)d * GD);
    }
    k_final<<<(GD + 255) / 256, 256, 0, stream>>>(out);
}